// Round 2
// baseline (189.689 us; speedup 1.0000x reference)
//
#include <hip/hip_runtime.h>
#include <stdint.h>

#define BATCH 4
#define SEQ   2048
#define FDIM  512
#define NHEAD 8
#define HDIM  64
#define KNN   32

typedef unsigned int u32;
typedef unsigned long long u64;
typedef unsigned short u16;
typedef unsigned short bf16_t;

typedef __attribute__((ext_vector_type(8))) short short8;   // 8 bf16 = 4 VGPRs
typedef __attribute__((ext_vector_type(4))) float f32x4;
typedef __attribute__((ext_vector_type(2))) __bf16 bf16x2;

#define SF  ((size_t)SEQ * FDIM)            // 1,048,576 per-batch elements
#define BSF ((size_t)BATCH * SF)            // 4,194,304

// fused_ck grid layout
#define CAST_NB 2432                        // 2048 (x) + 3*128 (weights)
#define XPART_NB 128                        // 4 batches x 32 chunks

__device__ __forceinline__ bf16_t f2bf(float f) {
    u32 x = __float_as_uint(f);
    return (bf16_t)((x + 0x7FFFu + ((x >> 16) & 1u)) >> 16);   // RNE
}
__device__ __forceinline__ float bf2f(bf16_t u) { return __uint_as_float(((u32)u) << 16); }
__device__ __forceinline__ void bf2x2(u32 p, float& a, float& b) {
    a = __uint_as_float(p << 16);          // element 2i (low u16)
    b = __uint_as_float(p & 0xFFFF0000u);  // element 2i+1 (high u16)
}
__device__ __forceinline__ u64 min_u64(u64 a, u64 b) { return a < b ? a : b; }
__device__ __forceinline__ u64 shfl_xor_u64(u64 v, int m) {
    int lo = __shfl_xor((int)(u32)v, m, 64);
    int hi = __shfl_xor((int)(u32)(v >> 32), m, 64);
    return (((u64)(u32)hi) << 32) | (u32)lo;
}

// packed bf16 pair dot: acc += a0*b0 + a1*b1 (fp32 accumulate)
__device__ __forceinline__ float dot2bf(u32 a, u32 b, float c) {
#if __has_builtin(__builtin_amdgcn_fdot2_f32_bf16)
    return __builtin_amdgcn_fdot2_f32_bf16(__builtin_bit_cast(bf16x2, a),
                                           __builtin_bit_cast(bf16x2, b), c, false);
#else
    float a0, a1, b0, b1;
    bf2x2(a, a0, a1); bf2x2(b, b0, b1);
    return c + a0 * b0 + a1 * b1;
#endif
}

// DPP lane permute (VALU pipe, no LDS): CTRL 0xB1=xor1, 0x4E=xor2,
// 0x141=row_half_mirror (xor7 -> combines 4-groups), 0x140=row_mirror (xor15).
template <int CTRL>
__device__ __forceinline__ float dppf(float x) {
    return __int_as_float(__builtin_amdgcn_update_dpp(
        0, __float_as_int(x), CTRL, 0xF, 0xF, true));
}

// ---------------------------------------------------------------------------
// cast body: fp32 -> bf16, 8 elem/thread. Linear block id selects tensor.
// ---------------------------------------------------------------------------
__device__ __forceinline__ void cast_body(int cid,
                                          const float* __restrict__ x,
                                          const float* __restrict__ wq,
                                          const float* __restrict__ wk,
                                          const float* __restrict__ wv,
                                          bf16_t* __restrict__ xb,
                                          bf16_t* __restrict__ wqb,
                                          bf16_t* __restrict__ wkb,
                                          bf16_t* __restrict__ wvb) {
    int z, blk;
    if (cid < 2048) { z = 0; blk = cid; }
    else { int d = cid - 2048; z = 1 + (d >> 7); blk = d & 127; }
    const float* src = (z == 0) ? x : (z == 1) ? wq : (z == 2) ? wk : wv;
    bf16_t* dst      = (z == 0) ? xb : (z == 1) ? wqb : (z == 2) ? wkb : wvb;
    size_t idx = (size_t)blk * 256 + threadIdx.x;
    const float4 a = ((const float4*)src)[idx * 2 + 0];
    const float4 b = ((const float4*)src)[idx * 2 + 1];
    uint4 o;
    o.x = (u32)f2bf(a.x) | ((u32)f2bf(a.y) << 16);
    o.y = (u32)f2bf(a.z) | ((u32)f2bf(a.w) << 16);
    o.z = (u32)f2bf(b.x) | ((u32)f2bf(b.y) << 16);
    o.w = (u32)f2bf(b.z) | ((u32)f2bf(b.w) << 16);
    ((uint4*)dst)[idx] = o;
}

// ---------------------------------------------------------------------------
// xpart body: per-(batch,chunk) partial column-mean of x -> xpart slot.
// ---------------------------------------------------------------------------
__device__ __forceinline__ void xpart_body(int id, const float* __restrict__ x,
                                           float* __restrict__ xpart) {
    const int b = id >> 5, chunk = id & 31;
    const int tid = threadIdx.x;
    const float* xp = x + (size_t)b * SF + (size_t)chunk * 64 * FDIM;
    float s0 = 0.f, s1 = 0.f;
    for (int r = 0; r < 64; ++r) {
        s0 += xp[(size_t)r * FDIM + tid];
        s1 += xp[(size_t)r * FDIM + tid + 256];
    }
    float* dst = xpart + (size_t)id * FDIM;
    dst[tid]       = s0 * (1.f / 2048.f);
    dst[tid + 256] = s1 * (1.f / 2048.f);
}

// ---------------------------------------------------------------------------
// kNN body (HW-validated r14): exact SET selection via two-level histogram.
// ---------------------------------------------------------------------------
__device__ __forceinline__ void knn_body(char* smem, int blk,
                                         const float* __restrict__ coords,
                                         u16* __restrict__ nn_out) {
    u32* chist = (u32*)smem;                  // 64  u32
    u32* fhist = (u32*)(smem + 256);          // 256 u32
    u64* bk    = (u64*)(smem + 1280);         // 64  u64
    u64* wpart = (u64*)(smem + 1792);         // 4   u64
    u32* sc    = (u32*)(smem + 1824);         // 8   u32
    const int b   = blk >> 11;
    const int qi  = blk & (SEQ - 1);
    const int t   = threadIdx.x;
    const int wid = t >> 6, lane = t & 63;
    const size_t qb = (size_t)blk * KNN;

    fhist[t & 255] = 0;
    if (t < 64) chist[t] = 0;
    if (t == 0) { sc[2] = 0; sc[3] = 0; }

    const float* cb = coords + (size_t)b * SEQ * 3;
    const float qx = cb[qi * 3 + 0];
    const float qy = cb[qi * 3 + 1];
    const float qz = cb[qi * 3 + 2];

    float dist[8];
    int   ib[8];
    u64 tmin = ~0ull;
#pragma unroll
    for (int i = 0; i < 8; ++i) {
        int c = i * 256 + t;
        float dx = __fsub_rn(cb[c * 3 + 0], qx);
        float dy = __fsub_rn(cb[c * 3 + 1], qy);
        float dz = __fsub_rn(cb[c * 3 + 2], qz);
        float d2 = __fadd_rn(__fadd_rn(__fmul_rn(dx, dx), __fmul_rn(dy, dy)),
                             __fmul_rn(dz, dz));
        dist[i] = __fsqrt_rn(d2);
        ib[i] = (int)(dist[i] * 8192.0f);
        u64 key = (((u64)__float_as_uint(dist[i])) << 32) | (u32)c;
        tmin = min_u64(tmin, key);
    }
    tmin = min_u64(tmin, shfl_xor_u64(tmin, 1));
    tmin = min_u64(tmin, shfl_xor_u64(tmin, 2));
    tmin = min_u64(tmin, shfl_xor_u64(tmin, 4));
    tmin = min_u64(tmin, shfl_xor_u64(tmin, 8));
    tmin = min_u64(tmin, shfl_xor_u64(tmin, 16));
    tmin = min_u64(tmin, shfl_xor_u64(tmin, 32));
    if (lane == 0) wpart[wid] = tmin;
    __syncthreads();                                  // B1

#pragma unroll
    for (int i = 0; i < 8; ++i) atomicAdd(&chist[ib[i] >> 8], 1u);
    const u64 M = min_u64(min_u64(wpart[0], wpart[1]),
                          min_u64(wpart[2], wpart[3]));
    __syncthreads();                                  // B2

    if (t < 64) {
        u32 h = chist[t];
        u32 cum = h;
#pragma unroll
        for (int d = 1; d < 64; d <<= 1) {
            u32 v = (u32)__shfl_up((int)cum, d, 64);
            if (t >= d) cum += v;
        }
        u64 bal = __ballot(cum >= 33);
        int Bc = __ffsll((long long)bal) - 1;
        u32 excl = cum - h;
        u32 base = (u32)__shfl((int)excl, Bc, 64);
        if (t == 0) { sc[0] = (u32)Bc; sc[1] = base; }
    }
    __syncthreads();                                  // B3

    {
        const int Bc = (int)sc[0];
#pragma unroll
        for (int i = 0; i < 8; ++i)
            if ((ib[i] >> 8) == Bc) atomicAdd(&fhist[ib[i] & 255], 1u);
    }
    __syncthreads();                                  // B4

    if (t < 64) {
        const u32 Bc = sc[0], base = sc[1];
        u32 f0 = fhist[t * 4 + 0], f1 = fhist[t * 4 + 1];
        u32 f2 = fhist[t * 4 + 2], f3 = fhist[t * 4 + 3];
        u32 s = f0 + f1 + f2 + f3;
        u32 cum = s;
#pragma unroll
        for (int d = 1; d < 64; d <<= 1) {
            u32 v = (u32)__shfl_up((int)cum, d, 64);
            if (t >= d) cum += v;
        }
        u32 E = base + (cum - s);
        u32 c0 = E + f0, c1 = c0 + f1, c2 = c1 + f2, c3 = c2 + f3;
        u64 bal = __ballot(c3 >= 33);
        int L = __ffsll((long long)bal) - 1;
        if (t == L) {
            int j = (c0 >= 33) ? 0 : (c1 >= 33) ? 1 : (c2 >= 33) ? 2 : 3;
            sc[4] = (Bc << 8) | (u32)(t * 4 + j);     // IBT
        }
    }
    __syncthreads();                                  // B5

    {
        const int ibt = (int)sc[4];
#pragma unroll
        for (int i = 0; i < 8; ++i) {
            int c = i * 256 + t;
            u64 key = (((u64)__float_as_uint(dist[i])) << 32) | (u32)c;
            if (ib[i] < ibt) {
                if (key != M) {
                    u32 pos = atomicAdd(&sc[2], 1u);
                    nn_out[qb + pos] = (u16)c;
                }
            } else if (ib[i] == ibt) {
                u32 bp = atomicAdd(&sc[3], 1u);
                if (bp < 64) bk[bp] = key;
            }
        }
    }
    __syncthreads();                                  // B6

    if (t < 64) {
        const u32 m = sc[2];
        const int n = (int)min(sc[3], 64u);
        const int need = 32 - (int)m;
        u64 k = (t < n) ? bk[t] : ~0ull;
        if (k == M) k = ~0ull;
#pragma unroll 1
        for (int r = 0; r < need; ++r) {
            u64 g = k;
            g = min_u64(g, shfl_xor_u64(g, 1));
            g = min_u64(g, shfl_xor_u64(g, 2));
            g = min_u64(g, shfl_xor_u64(g, 4));
            g = min_u64(g, shfl_xor_u64(g, 8));
            g = min_u64(g, shfl_xor_u64(g, 16));
            g = min_u64(g, shfl_xor_u64(g, 32));
            if (k == g) {
                nn_out[qb + m + r] = (u16)(g & 0x7FF);
                k = ~0ull;
            }
        }
    }
}

// ---------------------------------------------------------------------------
// FUSED dispatch 1: cast + xpart + knn.
// ---------------------------------------------------------------------------
__global__ __launch_bounds__(256) void fused_ck(const float* __restrict__ x,
                                                const float* __restrict__ wq,
                                                const float* __restrict__ wk,
                                                const float* __restrict__ wv,
                                                bf16_t* __restrict__ xb,
                                                bf16_t* __restrict__ wqb,
                                                bf16_t* __restrict__ wkb,
                                                bf16_t* __restrict__ wvb,
                                                const float* __restrict__ coords,
                                                u16* __restrict__ nn_out,
                                                float* __restrict__ xpart) {
    __shared__ __align__(16) char smem[1856];   // knn scratch only
    const int bid = blockIdx.x;
    if (bid < CAST_NB) {
        cast_body(bid, x, wq, wk, wv, xb, wqb, wkb, wvb);
    } else if (bid < CAST_NB + XPART_NB) {
        xpart_body(bid - CAST_NB, x, xpart);
    } else {
        knn_body(smem, bid - CAST_NB - XPART_NB, coords, nn_out);
    }
}

// ---------------------------------------------------------------------------
// Dispatch 2: GEMM + metric tail slab (z==3).
// z=0 -> q (NOW bf16 u16 into per-(q,h) cells of d_out); z=1,2 -> k,v (bf16
// to ws); z=3 -> metric.
// q cell layout: token's 2048B out row = 8 cells of 256B (one per head);
// q[token][h][d] bf16 stored at u16 index token*1024 + h*128 + d, i.e. the
// FIRST 128B of the cell that the SAME attn wave later overwrites with fp32
// out. Single-owner per cell -> no cross-wave hazard.
// ---------------------------------------------------------------------------
__global__ __launch_bounds__(256) void gemm_mfma(const bf16_t* __restrict__ xb,
                                                 const bf16_t* __restrict__ wqb,
                                                 const bf16_t* __restrict__ wkb,
                                                 const bf16_t* __restrict__ wvb,
                                                 float* __restrict__ qout,
                                                 bf16_t* __restrict__ kvout,
                                                 const float* __restrict__ xpart,
                                                 const float* __restrict__ Wkf,
                                                 float* __restrict__ metric) {
    __shared__ __align__(16) bf16_t As[128 * 32];
    __shared__ __align__(16) bf16_t Bs[128 * 32];
    const int z = blockIdx.z;
    const int tid  = threadIdx.x;

    if (z == 3) {                         // ---- metric tail ----
        const int id = blockIdx.y * 4 + blockIdx.x;    // 0..255
        if (id >= 8) return;
        float* xbarL = (float*)As;
        const int b = id >> 1;
        float a0 = 0.f, a1 = 0.f;
#pragma unroll 4
        for (int c = 0; c < 32; ++c) {
            const float* xp = xpart + (size_t)((b << 5) | c) * FDIM;
            a0 += xp[tid];
            a1 += xp[tid + 256];
        }
        xbarL[tid] = a0; xbarL[tid + 256] = a1;
        __syncthreads();
        const int f = ((id & 1) << 8) | tid;
        const float* wr = Wkf + (size_t)f * FDIM;
        float acc = 0.f;
#pragma unroll 4
        for (int kk = 0; kk < FDIM; kk += 4) {
            float4 wv = *(const float4*)(wr + kk);
            acc += xbarL[kk + 0] * wv.x + xbarL[kk + 1] * wv.y
                 + xbarL[kk + 2] * wv.z + xbarL[kk + 3] * wv.w;
        }
        metric[(b << 9) | f] = acc;
        return;
    }

    const bf16_t* W = (z == 0) ? wqb : (z == 1) ? wkb : wvb;
    const int wid  = tid >> 6, lane = tid & 63;
    const int m16  = lane & 15, quad = lane >> 4;
    const int wm   = (wid & 1) * 64;
    const int wn   = (wid >> 1) * 64;
    const int m0   = blockIdx.y * 128;
    const int n0   = blockIdx.x * 128;

    const int sr = tid >> 2, sc = (tid & 3) * 8;
    const bf16_t* agp = xb + (size_t)(m0 + sr) * FDIM + sc;
    const bf16_t* bgp = W  + (size_t)(n0 + sr) * FDIM + sc;

    f32x4 acc[4][4];
#pragma unroll
    for (int i = 0; i < 4; ++i)
#pragma unroll
        for (int j = 0; j < 4; ++j) acc[i][j] = (f32x4){0.f, 0.f, 0.f, 0.f};

#pragma unroll 1
    for (int k0 = 0; k0 < FDIM; k0 += 32) {
        uint4 a0 = *(const uint4*)(agp + k0);
        uint4 a1 = *(const uint4*)(agp + (size_t)64 * FDIM + k0);
        uint4 b0 = *(const uint4*)(bgp + k0);
        uint4 b1 = *(const uint4*)(bgp + (size_t)64 * FDIM + k0);
        __syncthreads();
        *(uint4*)(As + sr * 32 + sc)        = a0;
        *(uint4*)(As + (sr + 64) * 32 + sc) = a1;
        *(uint4*)(Bs + sr * 32 + sc)        = b0;
        *(uint4*)(Bs + (sr + 64) * 32 + sc) = b1;
        __syncthreads();

        short8 af[4], bfr[4];
#pragma unroll
        for (int i = 0; i < 4; ++i)
            af[i] = *(const short8*)(As + (wm + i * 16 + m16) * 32 + quad * 8);
#pragma unroll
        for (int j = 0; j < 4; ++j)
            bfr[j] = *(const short8*)(Bs + (wn + j * 16 + m16) * 32 + quad * 8);
#pragma unroll
        for (int i = 0; i < 4; ++i)
#pragma unroll
            for (int j = 0; j < 4; ++j)
                acc[i][j] = __builtin_amdgcn_mfma_f32_16x16x32_bf16(af[i], bfr[j],
                                                                    acc[i][j], 0, 0, 0);
    }

    if (z == 0) {
        u16* qb16 = (u16*)qout;
#pragma unroll
        for (int i = 0; i < 4; ++i) {
            const int rowb = m0 + wm + i * 16 + quad * 4;
#pragma unroll
            for (int r = 0; r < 4; ++r) {
                u16* orow = qb16 + (size_t)(rowb + r) * (2 * FDIM);
#pragma unroll
                for (int jj = 0; jj < 4; ++jj) {
                    const int col = n0 + wn + m16 + jj * 16;
                    orow[((col >> 6) << 7) + (col & 63)] = f2bf(acc[i][jj][r]);
                }
            }
        }
    } else {
        bf16_t* base = kvout + (size_t)(z - 1) * BSF;
#pragma unroll
        for (int i = 0; i < 4; ++i) {
            const int rowb = m0 + wm + i * 16 + quad * 4;
#pragma unroll
            for (int r = 0; r < 4; ++r) {
                bf16_t* orow = base + (size_t)(rowb + r) * FDIM + n0 + wn + m16;
                orow[ 0] = f2bf(acc[i][0][r]); orow[16] = f2bf(acc[i][1][r]);
                orow[32] = f2bf(acc[i][2][r]); orow[48] = f2bf(acc[i][3][r]);
            }
        }
    }
}

// ---------------------------------------------------------------------------
// Dispatch 3: Attention v5 — packed-bf16 q (dot2) + DPP softmax.
// One wave per (q,h); q read as 32 packed-bf16 u32 words from its own out
// cell; QK dot = 16 v_dot2_f32_bf16 (no unpack); softmax reductions use
// DPP (VALU pipe) for xor1/2/4/8 + one shfl_xor(16).
// ---------------------------------------------------------------------------
__global__ __launch_bounds__(256, 8) void attn_kernel(const bf16_t* __restrict__ kv,
                                                      const u16* __restrict__ nn,
                                                      float* __restrict__ out) {
    __shared__ __align__(16) u32 qslu[4][32];             // 512 B, per-wave slot
    const int i   = blockIdx.x;                           // 0..16383
    const int b   = (i & 7) >> 1;                         // XCD pair -> batch
    const int jb  = ((i >> 3) << 1) | (i & 1);            // 0..4095, bijective
    const int tid = threadIdx.x;
    const int wid = tid >> 6, lane = tid & 63;
    const int gid = (jb << 2) | wid;                      // 0..16383 per batch
    const int qi  = gid >> 3, h = gid & 7;
    const int blk = (b << 11) | qi;

    int sreg = 0;
    if (lane < 32) {
        sreg = (int)nn[(size_t)blk * KNN + lane] & (SEQ - 1);
        // q slice: first 128B of this wave's own out cell, packed bf16 pairs
        qslu[wid][lane] = ((const u32*)out)[(size_t)blk * FDIM + h * HDIM + lane];
    }
    __asm__ volatile("s_waitcnt lgkmcnt(0)" ::: "memory");
    __builtin_amdgcn_wave_barrier();

    const int j = lane & 31, half = lane >> 5;
    const int rowj = __shfl(sreg, j, 64);
    const bf16_t* kreg = kv + ((size_t)((b << 11) + rowj)) * FDIM + h * HDIM + half * 32;
    uint4 k0 = *(const uint4*)(kreg + 0);
    uint4 k1 = *(const uint4*)(kreg + 8);
    uint4 k2 = *(const uint4*)(kreg + 16);
    uint4 k3 = *(const uint4*)(kreg + 24);

    const int g = lane >> 4, l = lane & 15;
    const bf16_t* vbase = kv + BSF + ((size_t)(b << 11)) * FDIM + h * HDIM + l * 4;
    uint2 vv[8];
#pragma unroll
    for (int t2 = 0; t2 < 8; ++t2) {
        const int row = __shfl(sreg, (g << 3) | t2, 64);
        vv[t2] = *(const uint2*)(vbase + (size_t)row * FDIM);   // 4 bf16
    }

    // QK dot: 16 packed dot2 ops, two independent accumulator chains
    const u32* qp = &qslu[wid][half * 16];
    float a0 = 0.f, a1 = 0.f;
    a0 = dot2bf(qp[0],  k0.x, a0); a1 = dot2bf(qp[1],  k0.y, a1);
    a0 = dot2bf(qp[2],  k0.z, a0); a1 = dot2bf(qp[3],  k0.w, a1);
    a0 = dot2bf(qp[4],  k1.x, a0); a1 = dot2bf(qp[5],  k1.y, a1);
    a0 = dot2bf(qp[6],  k1.z, a0); a1 = dot2bf(qp[7],  k1.w, a1);
    a0 = dot2bf(qp[8],  k2.x, a0); a1 = dot2bf(qp[9],  k2.y, a1);
    a0 = dot2bf(qp[10], k2.z, a0); a1 = dot2bf(qp[11], k2.w, a1);
    a0 = dot2bf(qp[12], k3.x, a0); a1 = dot2bf(qp[13], k3.y, a1);
    a0 = dot2bf(qp[14], k3.z, a0); a1 = dot2bf(qp[15], k3.w, a1);
    float acc = a0 + a1;
    acc += __shfl_xor(acc, 32, 64);
    float s = acc * 0.125f;                 // 1/sqrt(64)

    // softmax max over 32 neighbors: DPP butterfly (xor1,2 | xor7 | xor15) + xor16
    float m = s;
    m = fmaxf(m, dppf<0xB1>(m));            // quad_perm xor1
    m = fmaxf(m, dppf<0x4E>(m));            // quad_perm xor2
    m = fmaxf(m, dppf<0x141>(m));           // row_half_mirror -> combines 4-groups
    m = fmaxf(m, dppf<0x140>(m));           // row_mirror -> combines 8-groups
    m = fmaxf(m, __shfl_xor(m, 16, 64));
    float e = __expf(s - m);
    float sum = e;
    sum += dppf<0xB1>(sum);
    sum += dppf<0x4E>(sum);
    sum += dppf<0x141>(sum);
    sum += dppf<0x140>(sum);
    sum += __shfl_xor(sum, 16, 64);
    float w = e / sum;                      // valid per j on lanes j and j+32

    float o0 = 0.f, o1 = 0.f, o2 = 0.f, o3 = 0.f;
#pragma unroll
    for (int t2 = 0; t2 < 8; ++t2) {
        const float wj = __shfl(w, (g << 3) | t2, 64);
        float f0, f1, f2, f3;
        bf2x2(vv[t2].x, f0, f1); bf2x2(vv[t2].y, f2, f3);
        o0 += wj * f0; o1 += wj * f1; o2 += wj * f2; o3 += wj * f3;
    }
    o0 += __shfl_xor(o0, 16, 64); o0 += __shfl_xor(o0, 32, 64);
    o1 += __shfl_xor(o1, 16, 64); o1 += __shfl_xor(o1, 32, 64);
    o2 += __shfl_xor(o2, 16, 64); o2 += __shfl_xor(o2, 32, 64);
    o3 += __shfl_xor(o3, 16, 64); o3 += __shfl_xor(o3, 32, 64);
    if (g == 0) {
        float4 ov = make_float4(o0, o1, o2, o3);
        *(float4*)(out + (size_t)blk * FDIM + h * HDIM + l * 4) = ov;
    }
}

// ---------------------------------------------------------------------------
extern "C" void kernel_launch(void* const* d_in, const int* in_sizes, int n_in,
                              void* d_out, int out_size, void* d_ws, size_t ws_size,
                              hipStream_t stream) {
    const float* x      = (const float*)d_in[0];
    const float* coords = (const float*)d_in[1];
    const float* Wq     = (const float*)d_in[2];
    const float* Wk     = (const float*)d_in[3];
    const float* Wv     = (const float*)d_in[4];
    float* out    = (float*)d_out;
    float* metric = out + BSF;

    // ws layout (~26.3 MiB):
    //   xb bf16 BSF (8 MiB) | wqb/wkb/wvb bf16 (1.5 MiB) | kv bf16 2*BSF (16 MiB)
    //   | nn u16 (0.5 MiB) | xpart f32 128*512 (256 KiB)
    char* p = (char*)d_ws;
    bf16_t* xb    = (bf16_t*)p;                      p += BSF * sizeof(bf16_t);
    bf16_t* wqb   = (bf16_t*)p;                      p += (size_t)FDIM * FDIM * sizeof(bf16_t);
    bf16_t* wkb   = (bf16_t*)p;                      p += (size_t)FDIM * FDIM * sizeof(bf16_t);
    bf16_t* wvb   = (bf16_t*)p;                      p += (size_t)FDIM * FDIM * sizeof(bf16_t);
    bf16_t* kv    = (bf16_t*)p;                      p += 2 * BSF * sizeof(bf16_t);
    u16*    nn    = (u16*)p;                         p += (size_t)BATCH * SEQ * KNN * sizeof(u16);
    float*  xpart = (float*)p;

    // 1) cast + xpart + knn
    fused_ck<<<CAST_NB + XPART_NB + BATCH * SEQ, 256, 0, stream>>>(
        x, Wq, Wk, Wv, xb, wqb, wkb, wvb, coords, nn, xpart);

    // 2) gemm (q -> d_out bf16 cells, k/v -> ws bf16) + metric tail (z==3)
    gemm_mfma<<<dim3(FDIM / 128, (BATCH * SEQ) / 128, 4), 256, 0, stream>>>(
        xb, wqb, wkb, wvb, out, kv, xpart, Wk, metric);

    // 3) attention standalone
    attn_kernel<<<BATCH * SEQ * NHEAD / 4, 256, 0, stream>>>(kv, nn, out);
}

// Round 3
// 163.034 us; speedup vs baseline: 1.1635x; 1.1635x over previous
//
#include <hip/hip_runtime.h>
#include <stdint.h>

#define BATCH 4
#define SEQ   2048
#define FDIM  512
#define NHEAD 8
#define HDIM  64
#define KNN   32

typedef unsigned int u32;
typedef unsigned long long u64;
typedef unsigned short u16;
typedef unsigned short bf16_t;

typedef __attribute__((ext_vector_type(8))) short short8;   // 8 bf16 = 4 VGPRs
typedef __attribute__((ext_vector_type(4))) float f32x4;

#define SF  ((size_t)SEQ * FDIM)            // 1,048,576 per-batch elements
#define BSF ((size_t)BATCH * SF)            // 4,194,304

// fused_ck grid layout
#define CAST_NB 2432                        // 2048 (x) + 3*128 (weights)
#define XPART_NB 128                        // 4 batches x 32 chunks

__device__ __forceinline__ bf16_t f2bf(float f) {
    u32 x = __float_as_uint(f);
    return (bf16_t)((x + 0x7FFFu + ((x >> 16) & 1u)) >> 16);   // RNE
}
__device__ __forceinline__ float bf2f(bf16_t u) { return __uint_as_float(((u32)u) << 16); }
__device__ __forceinline__ void bf2x2(u32 p, float& a, float& b) {
    a = __uint_as_float(p << 16);          // element 2i (low u16)
    b = __uint_as_float(p & 0xFFFF0000u);  // element 2i+1 (high u16)
}
__device__ __forceinline__ u64 min_u64(u64 a, u64 b) { return a < b ? a : b; }
__device__ __forceinline__ u64 shfl_xor_u64(u64 v, int m) {
    int lo = __shfl_xor((int)(u32)v, m, 64);
    int hi = __shfl_xor((int)(u32)(v >> 32), m, 64);
    return (((u64)(u32)hi) << 32) | (u32)lo;
}

// DPP lane permute (VALU pipe, no LDS): CTRL 0xB1=quad xor1, 0x4E=quad xor2,
// 0x141=row_half_mirror (other quad, reversed), 0x140=row_mirror (other 8-group,
// reversed, within 16-lane row). HW-validated round 2 (passed).
template <int CTRL>
__device__ __forceinline__ float dppf(float x) {
    return __int_as_float(__builtin_amdgcn_update_dpp(
        0, __float_as_int(x), CTRL, 0xF, 0xF, true));
}

// dot of 8 bf16 (packed in uint4) with 8 fp32 q values
__device__ __forceinline__ float dot8(uint4 k, f32x4 qa, f32x4 qb) {
    float f0, f1, f2, f3, f4, f5, f6, f7;
    bf2x2(k.x, f0, f1); bf2x2(k.y, f2, f3);
    bf2x2(k.z, f4, f5); bf2x2(k.w, f6, f7);
    return qa.x * f0 + qa.y * f1 + qa.z * f2 + qa.w * f3
         + qb.x * f4 + qb.y * f5 + qb.z * f6 + qb.w * f7;
}

// o[0..7] += w * unpack(v)
__device__ __forceinline__ void acc8(uint4 v, float w, float* o) {
    float f0, f1, f2, f3, f4, f5, f6, f7;
    bf2x2(v.x, f0, f1); bf2x2(v.y, f2, f3);
    bf2x2(v.z, f4, f5); bf2x2(v.w, f6, f7);
    o[0] += w * f0; o[1] += w * f1; o[2] += w * f2; o[3] += w * f3;
    o[4] += w * f4; o[5] += w * f5; o[6] += w * f6; o[7] += w * f7;
}

// ---------------------------------------------------------------------------
// cast body: fp32 -> bf16, 8 elem/thread. Linear block id selects tensor.
// ---------------------------------------------------------------------------
__device__ __forceinline__ void cast_body(int cid,
                                          const float* __restrict__ x,
                                          const float* __restrict__ wq,
                                          const float* __restrict__ wk,
                                          const float* __restrict__ wv,
                                          bf16_t* __restrict__ xb,
                                          bf16_t* __restrict__ wqb,
                                          bf16_t* __restrict__ wkb,
                                          bf16_t* __restrict__ wvb) {
    int z, blk;
    if (cid < 2048) { z = 0; blk = cid; }
    else { int d = cid - 2048; z = 1 + (d >> 7); blk = d & 127; }
    const float* src = (z == 0) ? x : (z == 1) ? wq : (z == 2) ? wk : wv;
    bf16_t* dst      = (z == 0) ? xb : (z == 1) ? wqb : (z == 2) ? wkb : wvb;
    size_t idx = (size_t)blk * 256 + threadIdx.x;
    const float4 a = ((const float4*)src)[idx * 2 + 0];
    const float4 b = ((const float4*)src)[idx * 2 + 1];
    uint4 o;
    o.x = (u32)f2bf(a.x) | ((u32)f2bf(a.y) << 16);
    o.y = (u32)f2bf(a.z) | ((u32)f2bf(a.w) << 16);
    o.z = (u32)f2bf(b.x) | ((u32)f2bf(b.y) << 16);
    o.w = (u32)f2bf(b.z) | ((u32)f2bf(b.w) << 16);
    ((uint4*)dst)[idx] = o;
}

// ---------------------------------------------------------------------------
// xpart body: per-(batch,chunk) partial column-mean of x -> xpart slot.
// ---------------------------------------------------------------------------
__device__ __forceinline__ void xpart_body(int id, const float* __restrict__ x,
                                           float* __restrict__ xpart) {
    const int b = id >> 5, chunk = id & 31;
    const int tid = threadIdx.x;
    const float* xp = x + (size_t)b * SF + (size_t)chunk * 64 * FDIM;
    float s0 = 0.f, s1 = 0.f;
    for (int r = 0; r < 64; ++r) {
        s0 += xp[(size_t)r * FDIM + tid];
        s1 += xp[(size_t)r * FDIM + tid + 256];
    }
    float* dst = xpart + (size_t)id * FDIM;
    dst[tid]       = s0 * (1.f / 2048.f);
    dst[tid + 256] = s1 * (1.f / 2048.f);
}

// ---------------------------------------------------------------------------
// kNN body (HW-validated r14): exact SET selection via two-level histogram.
// ---------------------------------------------------------------------------
__device__ __forceinline__ void knn_body(char* smem, int blk,
                                         const float* __restrict__ coords,
                                         u16* __restrict__ nn_out) {
    u32* chist = (u32*)smem;                  // 64  u32
    u32* fhist = (u32*)(smem + 256);          // 256 u32
    u64* bk    = (u64*)(smem + 1280);         // 64  u64
    u64* wpart = (u64*)(smem + 1792);         // 4   u64
    u32* sc    = (u32*)(smem + 1824);         // 8   u32
    const int b   = blk >> 11;
    const int qi  = blk & (SEQ - 1);
    const int t   = threadIdx.x;
    const int wid = t >> 6, lane = t & 63;
    const size_t qb = (size_t)blk * KNN;

    fhist[t & 255] = 0;
    if (t < 64) chist[t] = 0;
    if (t == 0) { sc[2] = 0; sc[3] = 0; }

    const float* cb = coords + (size_t)b * SEQ * 3;
    const float qx = cb[qi * 3 + 0];
    const float qy = cb[qi * 3 + 1];
    const float qz = cb[qi * 3 + 2];

    float dist[8];
    int   ib[8];
    u64 tmin = ~0ull;
#pragma unroll
    for (int i = 0; i < 8; ++i) {
        int c = i * 256 + t;
        float dx = __fsub_rn(cb[c * 3 + 0], qx);
        float dy = __fsub_rn(cb[c * 3 + 1], qy);
        float dz = __fsub_rn(cb[c * 3 + 2], qz);
        float d2 = __fadd_rn(__fadd_rn(__fmul_rn(dx, dx), __fmul_rn(dy, dy)),
                             __fmul_rn(dz, dz));
        dist[i] = __fsqrt_rn(d2);
        ib[i] = (int)(dist[i] * 8192.0f);
        u64 key = (((u64)__float_as_uint(dist[i])) << 32) | (u32)c;
        tmin = min_u64(tmin, key);
    }
    tmin = min_u64(tmin, shfl_xor_u64(tmin, 1));
    tmin = min_u64(tmin, shfl_xor_u64(tmin, 2));
    tmin = min_u64(tmin, shfl_xor_u64(tmin, 4));
    tmin = min_u64(tmin, shfl_xor_u64(tmin, 8));
    tmin = min_u64(tmin, shfl_xor_u64(tmin, 16));
    tmin = min_u64(tmin, shfl_xor_u64(tmin, 32));
    if (lane == 0) wpart[wid] = tmin;
    __syncthreads();                                  // B1

#pragma unroll
    for (int i = 0; i < 8; ++i) atomicAdd(&chist[ib[i] >> 8], 1u);
    const u64 M = min_u64(min_u64(wpart[0], wpart[1]),
                          min_u64(wpart[2], wpart[3]));
    __syncthreads();                                  // B2

    if (t < 64) {
        u32 h = chist[t];
        u32 cum = h;
#pragma unroll
        for (int d = 1; d < 64; d <<= 1) {
            u32 v = (u32)__shfl_up((int)cum, d, 64);
            if (t >= d) cum += v;
        }
        u64 bal = __ballot(cum >= 33);
        int Bc = __ffsll((long long)bal) - 1;
        u32 excl = cum - h;
        u32 base = (u32)__shfl((int)excl, Bc, 64);
        if (t == 0) { sc[0] = (u32)Bc; sc[1] = base; }
    }
    __syncthreads();                                  // B3

    {
        const int Bc = (int)sc[0];
#pragma unroll
        for (int i = 0; i < 8; ++i)
            if ((ib[i] >> 8) == Bc) atomicAdd(&fhist[ib[i] & 255], 1u);
    }
    __syncthreads();                                  // B4

    if (t < 64) {
        const u32 Bc = sc[0], base = sc[1];
        u32 f0 = fhist[t * 4 + 0], f1 = fhist[t * 4 + 1];
        u32 f2 = fhist[t * 4 + 2], f3 = fhist[t * 4 + 3];
        u32 s = f0 + f1 + f2 + f3;
        u32 cum = s;
#pragma unroll
        for (int d = 1; d < 64; d <<= 1) {
            u32 v = (u32)__shfl_up((int)cum, d, 64);
            if (t >= d) cum += v;
        }
        u32 E = base + (cum - s);
        u32 c0 = E + f0, c1 = c0 + f1, c2 = c1 + f2, c3 = c2 + f3;
        u64 bal = __ballot(c3 >= 33);
        int L = __ffsll((long long)bal) - 1;
        if (t == L) {
            int j = (c0 >= 33) ? 0 : (c1 >= 33) ? 1 : (c2 >= 33) ? 2 : 3;
            sc[4] = (Bc << 8) | (u32)(t * 4 + j);     // IBT
        }
    }
    __syncthreads();                                  // B5

    {
        const int ibt = (int)sc[4];
#pragma unroll
        for (int i = 0; i < 8; ++i) {
            int c = i * 256 + t;
            u64 key = (((u64)__float_as_uint(dist[i])) << 32) | (u32)c;
            if (ib[i] < ibt) {
                if (key != M) {
                    u32 pos = atomicAdd(&sc[2], 1u);
                    nn_out[qb + pos] = (u16)c;
                }
            } else if (ib[i] == ibt) {
                u32 bp = atomicAdd(&sc[3], 1u);
                if (bp < 64) bk[bp] = key;
            }
        }
    }
    __syncthreads();                                  // B6

    if (t < 64) {
        const u32 m = sc[2];
        const int n = (int)min(sc[3], 64u);
        const int need = 32 - (int)m;
        u64 k = (t < n) ? bk[t] : ~0ull;
        if (k == M) k = ~0ull;
#pragma unroll 1
        for (int r = 0; r < need; ++r) {
            u64 g = k;
            g = min_u64(g, shfl_xor_u64(g, 1));
            g = min_u64(g, shfl_xor_u64(g, 2));
            g = min_u64(g, shfl_xor_u64(g, 4));
            g = min_u64(g, shfl_xor_u64(g, 8));
            g = min_u64(g, shfl_xor_u64(g, 16));
            g = min_u64(g, shfl_xor_u64(g, 32));
            if (k == g) {
                nn_out[qb + m + r] = (u16)(g & 0x7FF);
                k = ~0ull;
            }
        }
    }
}

// ---------------------------------------------------------------------------
// FUSED dispatch 1: cast + xpart + knn.
// ---------------------------------------------------------------------------
__global__ __launch_bounds__(256) void fused_ck(const float* __restrict__ x,
                                                const float* __restrict__ wq,
                                                const float* __restrict__ wk,
                                                const float* __restrict__ wv,
                                                bf16_t* __restrict__ xb,
                                                bf16_t* __restrict__ wqb,
                                                bf16_t* __restrict__ wkb,
                                                bf16_t* __restrict__ wvb,
                                                const float* __restrict__ coords,
                                                u16* __restrict__ nn_out,
                                                float* __restrict__ xpart) {
    __shared__ __align__(16) char smem[1856];   // knn scratch only
    const int bid = blockIdx.x;
    if (bid < CAST_NB) {
        cast_body(bid, x, wq, wk, wv, xb, wqb, wkb, wvb);
    } else if (bid < CAST_NB + XPART_NB) {
        xpart_body(bid - CAST_NB, x, xpart);
    } else {
        knn_body(smem, bid - CAST_NB - XPART_NB, coords, nn_out);
    }
}

// ---------------------------------------------------------------------------
// Dispatch 2: GEMM (r15 HW-validated body, fp32 q epilogue RESTORED) +
// metric tail slab (z==3).
// ---------------------------------------------------------------------------
__global__ __launch_bounds__(256) void gemm_mfma(const bf16_t* __restrict__ xb,
                                                 const bf16_t* __restrict__ wqb,
                                                 const bf16_t* __restrict__ wkb,
                                                 const bf16_t* __restrict__ wvb,
                                                 float* __restrict__ qout,
                                                 bf16_t* __restrict__ kvout,
                                                 const float* __restrict__ xpart,
                                                 const float* __restrict__ Wkf,
                                                 float* __restrict__ metric) {
    __shared__ __align__(16) bf16_t As[128 * 32];
    __shared__ __align__(16) bf16_t Bs[128 * 32];
    const int z = blockIdx.z;
    const int tid  = threadIdx.x;

    if (z == 3) {                         // ---- metric tail ----
        const int id = blockIdx.y * 4 + blockIdx.x;    // 0..255
        if (id >= 8) return;
        float* xbarL = (float*)As;
        const int b = id >> 1;
        float a0 = 0.f, a1 = 0.f;
#pragma unroll 4
        for (int c = 0; c < 32; ++c) {
            const float* xp = xpart + (size_t)((b << 5) | c) * FDIM;
            a0 += xp[tid];
            a1 += xp[tid + 256];
        }
        xbarL[tid] = a0; xbarL[tid + 256] = a1;
        __syncthreads();
        const int f = ((id & 1) << 8) | tid;
        const float* wr = Wkf + (size_t)f * FDIM;
        float acc = 0.f;
#pragma unroll 4
        for (int kk = 0; kk < FDIM; kk += 4) {
            float4 wv = *(const float4*)(wr + kk);
            acc += xbarL[kk + 0] * wv.x + xbarL[kk + 1] * wv.y
                 + xbarL[kk + 2] * wv.z + xbarL[kk + 3] * wv.w;
        }
        metric[(b << 9) | f] = acc;
        return;
    }

    const bf16_t* W = (z == 0) ? wqb : (z == 1) ? wkb : wvb;
    const int wid  = tid >> 6, lane = tid & 63;
    const int m16  = lane & 15, quad = lane >> 4;
    const int wm   = (wid & 1) * 64;
    const int wn   = (wid >> 1) * 64;
    const int m0   = blockIdx.y * 128;
    const int n0   = blockIdx.x * 128;

    const int sr = tid >> 2, sc = (tid & 3) * 8;
    const bf16_t* agp = xb + (size_t)(m0 + sr) * FDIM + sc;
    const bf16_t* bgp = W  + (size_t)(n0 + sr) * FDIM + sc;

    f32x4 acc[4][4];
#pragma unroll
    for (int i = 0; i < 4; ++i)
#pragma unroll
        for (int j = 0; j < 4; ++j) acc[i][j] = (f32x4){0.f, 0.f, 0.f, 0.f};

#pragma unroll 1
    for (int k0 = 0; k0 < FDIM; k0 += 32) {
        uint4 a0 = *(const uint4*)(agp + k0);
        uint4 a1 = *(const uint4*)(agp + (size_t)64 * FDIM + k0);
        uint4 b0 = *(const uint4*)(bgp + k0);
        uint4 b1 = *(const uint4*)(bgp + (size_t)64 * FDIM + k0);
        __syncthreads();
        *(uint4*)(As + sr * 32 + sc)        = a0;
        *(uint4*)(As + (sr + 64) * 32 + sc) = a1;
        *(uint4*)(Bs + sr * 32 + sc)        = b0;
        *(uint4*)(Bs + (sr + 64) * 32 + sc) = b1;
        __syncthreads();

        short8 af[4], bfr[4];
#pragma unroll
        for (int i = 0; i < 4; ++i)
            af[i] = *(const short8*)(As + (wm + i * 16 + m16) * 32 + quad * 8);
#pragma unroll
        for (int j = 0; j < 4; ++j)
            bfr[j] = *(const short8*)(Bs + (wn + j * 16 + m16) * 32 + quad * 8);
#pragma unroll
        for (int i = 0; i < 4; ++i)
#pragma unroll
            for (int j = 0; j < 4; ++j)
                acc[i][j] = __builtin_amdgcn_mfma_f32_16x16x32_bf16(af[i], bfr[j],
                                                                    acc[i][j], 0, 0, 0);
    }

    if (z == 0) {
#pragma unroll
        for (int i = 0; i < 4; ++i) {
            const int rowb = m0 + wm + i * 16 + quad * 4;
#pragma unroll
            for (int r = 0; r < 4; ++r) {
                float* orow = qout + (size_t)(rowb + r) * FDIM + n0 + wn + m16;
                orow[ 0] = acc[i][0][r]; orow[16] = acc[i][1][r];
                orow[32] = acc[i][2][r]; orow[48] = acc[i][3][r];
            }
        }
    } else {
        bf16_t* base = kvout + (size_t)(z - 1) * BSF;
#pragma unroll
        for (int i = 0; i < 4; ++i) {
            const int rowb = m0 + wm + i * 16 + quad * 4;
#pragma unroll
            for (int r = 0; r < 4; ++r) {
                bf16_t* orow = base + (size_t)(rowb + r) * FDIM + n0 + wn + m16;
                orow[ 0] = f2bf(acc[i][0][r]); orow[16] = f2bf(acc[i][1][r]);
                orow[32] = f2bf(acc[i][2][r]); orow[48] = f2bf(acc[i][3][r]);
            }
        }
    }
}

// ---------------------------------------------------------------------------
// Dispatch 3: Attention v6 — cooperative 8-lanes-per-row gather.
// One wave per (q,h). Rows split into 4 sets of 8; lane (g3=lane>>3, l8=lane&7)
// reads 16B of row set*8+g3 at dim offset l8*8. Each K/V load instruction
// covers 8 rows x 128 B fully dense (16 x 64B segments vs 64 sparse before).
// QK dot: per-lane dot8 + 3-DPP tree over the 8-lane group. Softmax: 4 regs
// + row_mirror + xor16/32. PV: weights are lane-local (no shuffles); final
// cross-group reduce via 2 KB LDS per wave.
// ---------------------------------------------------------------------------
__global__ __launch_bounds__(256, 6) void attn_kernel(const bf16_t* __restrict__ kv,
                                                      const u16* __restrict__ nn,
                                                      float* __restrict__ out) {
    __shared__ float qsl[4][64];                          // 1 KB: per-wave q
    __shared__ float osl[4][8][64];                       // 8 KB: o partials
    const int i   = blockIdx.x;                           // 0..16383
    const int b   = (i & 7) >> 1;                         // XCD pair -> batch
    const int jb  = ((i >> 3) << 1) | (i & 1);            // 0..4095, bijective
    const int tid = threadIdx.x;
    const int wid = tid >> 6, lane = tid & 63;
    const int gid = (jb << 2) | wid;                      // 0..16383 per batch
    const int qi  = gid >> 3, h = gid & 7;
    const int blk = (b << 11) | qi;

    int sreg = 0;
    if (lane < KNN) sreg = (int)nn[(size_t)blk * KNN + lane] & (SEQ - 1);
    qsl[wid][lane] = out[(size_t)blk * FDIM + h * HDIM + lane];   // own q slice

    const int g3 = lane >> 3, l8 = lane & 7;
    const int r0 = __shfl(sreg,      g3, 64);
    const int r1 = __shfl(sreg,  8 + g3, 64);
    const int r2 = __shfl(sreg, 16 + g3, 64);
    const int r3 = __shfl(sreg, 24 + g3, 64);

    const bf16_t* base = kv + ((size_t)(b << 11)) * FDIM + h * HDIM + l8 * 8;
    const uint4 k0 = *(const uint4*)(base + (size_t)r0 * FDIM);
    const uint4 k1 = *(const uint4*)(base + (size_t)r1 * FDIM);
    const uint4 k2 = *(const uint4*)(base + (size_t)r2 * FDIM);
    const uint4 k3 = *(const uint4*)(base + (size_t)r3 * FDIM);
    const uint4 v0 = *(const uint4*)(base + BSF + (size_t)r0 * FDIM);
    const uint4 v1 = *(const uint4*)(base + BSF + (size_t)r1 * FDIM);
    const uint4 v2 = *(const uint4*)(base + BSF + (size_t)r2 * FDIM);
    const uint4 v3 = *(const uint4*)(base + BSF + (size_t)r3 * FDIM);

    __asm__ volatile("s_waitcnt lgkmcnt(0)" ::: "memory");
    __builtin_amdgcn_wave_barrier();
    const f32x4 qa = *(const f32x4*)&qsl[wid][l8 * 8];
    const f32x4 qb = *(const f32x4*)&qsl[wid][l8 * 8 + 4];

    // QK^T: per-lane partial dot (8 dims), then 3-step DPP tree over the
    // 8-lane group -> s uniform across the group.
    float s0 = dot8(k0, qa, qb);
    float s1 = dot8(k1, qa, qb);
    float s2 = dot8(k2, qa, qb);
    float s3 = dot8(k3, qa, qb);
    s0 += dppf<0xB1>(s0); s0 += dppf<0x4E>(s0); s0 += dppf<0x141>(s0);
    s1 += dppf<0xB1>(s1); s1 += dppf<0x4E>(s1); s1 += dppf<0x141>(s1);
    s2 += dppf<0xB1>(s2); s2 += dppf<0x4E>(s2); s2 += dppf<0x141>(s2);
    s3 += dppf<0xB1>(s3); s3 += dppf<0x4E>(s3); s3 += dppf<0x141>(s3);
    s0 *= 0.125f; s1 *= 0.125f; s2 *= 0.125f; s3 *= 0.125f;   // 1/sqrt(64)

    // softmax over 32 rows: per-lane 4 values, uniform within 8-groups.
    float ml = fmaxf(fmaxf(s0, s1), fmaxf(s2, s3));
    ml = fmaxf(ml, dppf<0x140>(ml));              // bit3 (uniform-in-8 safe)
    ml = fmaxf(ml, __shfl_xor(ml, 16, 64));
    ml = fmaxf(ml, __shfl_xor(ml, 32, 64));
    const float e0 = __expf(s0 - ml), e1 = __expf(s1 - ml);
    const float e2 = __expf(s2 - ml), e3 = __expf(s3 - ml);
    float sl = (e0 + e1) + (e2 + e3);
    sl += dppf<0x140>(sl);
    sl += __shfl_xor(sl, 16, 64);
    sl += __shfl_xor(sl, 32, 64);
    const float rs = 1.0f / sl;
    const float w0 = e0 * rs, w1 = e1 * rs, w2 = e2 * rs, w3 = e3 * rs;

    // PV: weights lane-local, V rows identical to K rows.
    float o[8] = {0.f, 0.f, 0.f, 0.f, 0.f, 0.f, 0.f, 0.f};
    acc8(v0, w0, o);
    acc8(v1, w1, o);
    acc8(v2, w2, o);
    acc8(v3, w3, o);

    // cross-group reduce (8 groups) via LDS, then coalesced store.
    *(f32x4*)&osl[wid][g3][l8 * 8]     = (f32x4){o[0], o[1], o[2], o[3]};
    *(f32x4*)&osl[wid][g3][l8 * 8 + 4] = (f32x4){o[4], o[5], o[6], o[7]};
    __asm__ volatile("s_waitcnt lgkmcnt(0)" ::: "memory");
    __builtin_amdgcn_wave_barrier();
    float r = osl[wid][0][lane];
#pragma unroll
    for (int g = 1; g < 8; ++g) r += osl[wid][g][lane];
    out[(size_t)blk * FDIM + h * HDIM + lane] = r;
}

// ---------------------------------------------------------------------------
extern "C" void kernel_launch(void* const* d_in, const int* in_sizes, int n_in,
                              void* d_out, int out_size, void* d_ws, size_t ws_size,
                              hipStream_t stream) {
    const float* x      = (const float*)d_in[0];
    const float* coords = (const float*)d_in[1];
    const float* Wq     = (const float*)d_in[2];
    const float* Wk     = (const float*)d_in[3];
    const float* Wv     = (const float*)d_in[4];
    float* out    = (float*)d_out;
    float* metric = out + BSF;

    // ws layout (~26.3 MiB):
    //   xb bf16 BSF (8 MiB) | wqb/wkb/wvb bf16 (1.5 MiB) | kv bf16 2*BSF (16 MiB)
    //   | nn u16 (0.5 MiB) | xpart f32 128*512 (256 KiB)
    char* p = (char*)d_ws;
    bf16_t* xb    = (bf16_t*)p;                      p += BSF * sizeof(bf16_t);
    bf16_t* wqb   = (bf16_t*)p;                      p += (size_t)FDIM * FDIM * sizeof(bf16_t);
    bf16_t* wkb   = (bf16_t*)p;                      p += (size_t)FDIM * FDIM * sizeof(bf16_t);
    bf16_t* wvb   = (bf16_t*)p;                      p += (size_t)FDIM * FDIM * sizeof(bf16_t);
    bf16_t* kv    = (bf16_t*)p;                      p += 2 * BSF * sizeof(bf16_t);
    u16*    nn    = (u16*)p;                         p += (size_t)BATCH * SEQ * KNN * sizeof(u16);
    float*  xpart = (float*)p;

    // 1) cast + xpart + knn
    fused_ck<<<CAST_NB + XPART_NB + BATCH * SEQ, 256, 0, stream>>>(
        x, Wq, Wk, Wv, xb, wqb, wkb, wvb, coords, nn, xpart);

    // 2) gemm (q -> d_out fp32, k/v -> ws bf16) + metric tail (z==3)
    gemm_mfma<<<dim3(FDIM / 128, (BATCH * SEQ) / 128, 4), 256, 0, stream>>>(
        xb, wqb, wkb, wvb, out, kv, xpart, Wk, metric);

    // 3) attention
    attn_kernel<<<BATCH * SEQ * NHEAD / 4, 256, 0, stream>>>(kv, nn, out);
}